// Round 2
// baseline (451.611 us; speedup 1.0000x reference)
//
#include <hip/hip_runtime.h>
#include <hip/hip_bf16.h>

// Shapes: B=4, T=8, C=64, H=32, W=32, F=16, N=T*H*W=8192, HW=1024.
// pooled[b,n] = sum_c wbar[c]*x[b,t,c,h,w] + bbar   (conv1+avgpool collapsed)
// v[b,n]      = sigmoid(pooled[b,:] . ffnn1_w[n,:] + ffnn1_b[n])
// out[b,t,f,h,w] = v[b,n] * (sum_c g3_w[f,c]*x[b,t,c,h,w] + g3_b[f])
//
// DTYPE-ROBUST: inputs may be bf16 (bf16-mode dataset) or float32 (literal
// reference dtype). A detect kernel classifies x's bit patterns and all
// compute kernels dispatch on the flag (uniform branch, templated bodies).

#define HW 1024
#define Cc 64
#define Ff 16
#define Nn 8192

typedef __hip_bfloat16 bf16;

__device__ __forceinline__ float bf2f(bf16 h) { return __bfloat162float(h); }

template <bool F32>
__device__ __forceinline__ float ld1(const void* p, int i) {
    if constexpr (F32) return ((const float*)p)[i];
    else               return bf2f(((const bf16*)p)[i]);
}

// ---------------- Kernel 0: dtype detect ----------------
// Even uint16 halfwords of a bf16 array are real bf16 N(0,1) values
// (exponent in [0x6F,0x83] ~always). For a float32 array they are low
// mantissa bits (~uniform: passes ~8% of the time). 256 samples, thresh 128.
__global__ void detect_kernel(const unsigned short* __restrict__ xs,
                              int* __restrict__ flag) {
    int tid = threadIdx.x;  // 64 threads
    int cnt = 0;
    #pragma unroll
    for (int i = 0; i < 4; ++i) {
        unsigned short u = xs[(tid * 4 + i) * 2];  // even halfword index
        int e = (u >> 7) & 0xFF;
        if (e >= 0x6F && e <= 0x83) cnt++;
    }
    #pragma unroll
    for (int off = 32; off > 0; off >>= 1) cnt += __shfl_down(cnt, off);
    if (tid == 0) flag[0] = (cnt < 128) ? 1 : 0;  // 1 => float32 inputs
}

// ---------------- Kernel 1: pooled ----------------
template <bool F32>
__device__ __forceinline__ void pool_body(const void* __restrict__ x,
                                          const void* __restrict__ conv1_w,
                                          const void* __restrict__ conv1_b,
                                          float* __restrict__ pooled) {
    __shared__ float wbar[Cc];
    __shared__ float bbar;
    int tid = threadIdx.x;
    if (tid < Cc) {
        float s = 0.f;
        #pragma unroll
        for (int f = 0; f < Ff; ++f) s += ld1<F32>(conv1_w, f * Cc + tid);
        wbar[tid] = s * (1.f / 16.f);
    }
    if (tid == 64) {
        float s = 0.f;
        #pragma unroll
        for (int f = 0; f < Ff; ++f) s += ld1<F32>(conv1_b, f);
        bbar = s * (1.f / 16.f);
    }
    __syncthreads();

    int bt = blockIdx.x >> 2;                 // 0..31 (b*8+t)
    int hw = ((blockIdx.x & 3) << 8) + tid;   // 0..1023
    size_t base = (size_t)bt * Cc * HW + hw;
    float acc = 0.f;
    #pragma unroll
    for (int c = 0; c < Cc; ++c) acc += wbar[c] * ld1<F32>(x, base + c * HW);

    int b = bt >> 3, t = bt & 7;
    pooled[b * Nn + t * HW + hw] = acc + bbar;
}

__global__ void pool_kernel(const void* __restrict__ x,
                            const void* __restrict__ conv1_w,
                            const void* __restrict__ conv1_b,
                            float* __restrict__ pooled,
                            const int* __restrict__ flag) {
    if (flag[0]) pool_body<true>(x, conv1_w, conv1_b, pooled);
    else         pool_body<false>(x, conv1_w, conv1_b, pooled);
}

// ---------------- Kernel 2: v = sigmoid(pooled @ W^T + b) ----------------
template <bool F32>
__device__ __forceinline__ void gemv_body(const void* __restrict__ w,
                                          const void* __restrict__ bias,
                                          const float* __restrict__ pooled,
                                          float* __restrict__ v) {
    int n = blockIdx.x;
    int tid = threadIdx.x;
    float acc[4] = {0.f, 0.f, 0.f, 0.f};

    #pragma unroll
    for (int j = 0; j < 4; ++j) {
        int k = j * 2048 + tid * 8;  // 8 elements per lane per iter
        float wv[8];
        if constexpr (F32) {
            const float* row = (const float*)w + (size_t)n * Nn;
            float4 w0 = *reinterpret_cast<const float4*>(row + k);
            float4 w1 = *reinterpret_cast<const float4*>(row + k + 4);
            wv[0] = w0.x; wv[1] = w0.y; wv[2] = w0.z; wv[3] = w0.w;
            wv[4] = w1.x; wv[5] = w1.y; wv[6] = w1.z; wv[7] = w1.w;
        } else {
            const bf16* row = (const bf16*)w + (size_t)n * Nn;
            uint4 q = *reinterpret_cast<const uint4*>(row + k);
            wv[0] = __uint_as_float(q.x << 16);
            wv[1] = __uint_as_float(q.x & 0xffff0000u);
            wv[2] = __uint_as_float(q.y << 16);
            wv[3] = __uint_as_float(q.y & 0xffff0000u);
            wv[4] = __uint_as_float(q.z << 16);
            wv[5] = __uint_as_float(q.z & 0xffff0000u);
            wv[6] = __uint_as_float(q.w << 16);
            wv[7] = __uint_as_float(q.w & 0xffff0000u);
        }
        #pragma unroll
        for (int b = 0; b < 4; ++b) {
            const float* pp = pooled + b * Nn + k;
            float4 p0 = *reinterpret_cast<const float4*>(pp);
            float4 p1 = *reinterpret_cast<const float4*>(pp + 4);
            acc[b] += wv[0] * p0.x + wv[1] * p0.y + wv[2] * p0.z + wv[3] * p0.w
                    + wv[4] * p1.x + wv[5] * p1.y + wv[6] * p1.z + wv[7] * p1.w;
        }
    }

    #pragma unroll
    for (int b = 0; b < 4; ++b) {
        #pragma unroll
        for (int off = 32; off > 0; off >>= 1)
            acc[b] += __shfl_down(acc[b], off);
    }
    __shared__ float red[4][4];  // [wave][b]
    int wave = tid >> 6, lane = tid & 63;
    if (lane == 0) {
        red[wave][0] = acc[0]; red[wave][1] = acc[1];
        red[wave][2] = acc[2]; red[wave][3] = acc[3];
    }
    __syncthreads();
    if (tid == 0) {
        float bn = ld1<F32>(bias, n);
        #pragma unroll
        for (int b = 0; b < 4; ++b) {
            float s = red[0][b] + red[1][b] + red[2][b] + red[3][b] + bn;
            v[b * Nn + n] = 1.f / (1.f + __expf(-s));
        }
    }
}

__global__ void gemv_kernel(const void* __restrict__ w,
                            const void* __restrict__ bias,
                            const float* __restrict__ pooled,
                            float* __restrict__ v,
                            const int* __restrict__ flag) {
    if (flag[0]) gemv_body<true>(w, bias, pooled, v);
    else         gemv_body<false>(w, bias, pooled, v);
}

// ---------------- Kernel 3: out = v * (g3_w . x + g3_b) ----------------
template <bool F32>
__device__ __forceinline__ void out_body(const void* __restrict__ x,
                                         const void* __restrict__ g3_w,
                                         const void* __restrict__ g3_b,
                                         const float* __restrict__ v,
                                         void* __restrict__ out) {
    __shared__ float ws[Ff][Cc];  // per-(f,c) reads are wave-uniform: broadcast
    __shared__ float bs[Ff];
    int tid = threadIdx.x;
    for (int i = tid; i < Ff * Cc; i += 256) ws[i >> 6][i & 63] = ld1<F32>(g3_w, i);
    if (tid < Ff) bs[tid] = ld1<F32>(g3_b, tid);
    __syncthreads();

    int bt = blockIdx.x >> 2;
    int hw = ((blockIdx.x & 3) << 8) + tid;
    size_t xbase = (size_t)bt * Cc * HW + hw;

    float xv[Cc];
    #pragma unroll
    for (int c = 0; c < Cc; ++c) xv[c] = ld1<F32>(x, xbase + c * HW);

    int b = bt >> 3, t = bt & 7;
    float vv = v[b * Nn + t * HW + hw];

    size_t obase = (size_t)bt * Ff * HW + hw;
    #pragma unroll
    for (int f = 0; f < Ff; ++f) {
        float acc = bs[f];
        #pragma unroll
        for (int c = 0; c < Cc; ++c) acc += ws[f][c] * xv[c];
        float r = vv * acc;
        if constexpr (F32) ((float*)out)[obase + f * HW] = r;
        else               ((bf16*)out)[obase + f * HW] = __float2bfloat16(r);
    }
}

__global__ void out_kernel(const void* __restrict__ x,
                           const void* __restrict__ g3_w,
                           const void* __restrict__ g3_b,
                           const float* __restrict__ v,
                           void* __restrict__ out,
                           const int* __restrict__ flag) {
    if (flag[0]) out_body<true>(x, g3_w, g3_b, v, out);
    else         out_body<false>(x, g3_w, g3_b, v, out);
}

extern "C" void kernel_launch(void* const* d_in, const int* in_sizes, int n_in,
                              void* d_out, int out_size, void* d_ws, size_t ws_size,
                              hipStream_t stream) {
    const void* x       = d_in[0];
    // d_in[1] = x1 (unused by the reference forward)
    const void* conv1_w = d_in[2];
    const void* conv1_b = d_in[3];
    const void* g3_w    = d_in[4];
    const void* g3_b    = d_in[5];
    const void* ffnn1_w = d_in[6];
    const void* ffnn1_b = d_in[7];

    int*   flag   = (int*)d_ws;                    // 64 B slot
    float* pooled = (float*)d_ws + 16;             // 4*8192 floats = 128 KB
    float* v      = pooled + 4 * Nn;               // 4*8192 floats = 128 KB

    detect_kernel<<<1, 64, 0, stream>>>((const unsigned short*)x, flag);
    pool_kernel<<<128, 256, 0, stream>>>(x, conv1_w, conv1_b, pooled, flag);
    gemv_kernel<<<Nn, 256, 0, stream>>>(ffnn1_w, ffnn1_b, pooled, v, flag);
    out_kernel<<<128, 256, 0, stream>>>(x, g3_w, g3_b, v, d_out, flag);
}

// Round 3
// 411.824 us; speedup vs baseline: 1.0966x; 1.0966x over previous
//
#include <hip/hip_runtime.h>
#include <hip/hip_bf16.h>

// Shapes: B=4, T=8, C=64, H=32, W=32, F=16, N=T*H*W=8192, HW=1024.
// pooled[b,n] = sum_c wbar[c]*x[b,t,c,h,w] + bbar   (conv1+avgpool collapsed)
// v[b,n]      = sigmoid(pooled[b,:] . ffnn1_w[n,:] + ffnn1_b[n])
// out[b,t,f,h,w] = v[b,n] * (sum_c g3_w[f,c]*x[b,t,c,h,w] + g3_b[f])
//
// DTYPE-ROBUST: inputs may be bf16 or float32. pool_kernel detects the dtype
// from x's bit patterns per-block (all blocks agree; benign same-value race on
// the global flag) and later kernels read the flag (stream-ordered).

#define HW 1024
#define Cc 64
#define Ff 16
#define Nn 8192

typedef __hip_bfloat16 bf16;

__device__ __forceinline__ float bf2f(bf16 h) { return __bfloat162float(h); }

template <bool F32>
__device__ __forceinline__ float ld1(const void* p, int i) {
    if constexpr (F32) return ((const float*)p)[i];
    else               return bf2f(((const bf16*)p)[i]);
}

// ---------------- Kernel 1: pooled (+ inline dtype detect) ----------------
// grid = 256 blocks x 128 threads. Each thread owns one (bt, hw) pair.
template <bool F32>
__device__ __forceinline__ void pool_body(const void* __restrict__ x,
                                          const void* __restrict__ conv1_w,
                                          const void* __restrict__ conv1_b,
                                          float* __restrict__ pooled) {
    __shared__ float wbar[Cc];
    __shared__ float bbar;
    int tid = threadIdx.x;  // 0..127
    if (tid < Cc) {
        float s = 0.f;
        #pragma unroll
        for (int f = 0; f < Ff; ++f) s += ld1<F32>(conv1_w, f * Cc + tid);
        wbar[tid] = s * (1.f / 16.f);
    }
    if (tid == 64) {
        float s = 0.f;
        #pragma unroll
        for (int f = 0; f < Ff; ++f) s += ld1<F32>(conv1_b, f);
        bbar = s * (1.f / 16.f);
    }
    __syncthreads();

    int bt = blockIdx.x >> 3;                  // 0..31 (b*8+t)
    int hw = ((blockIdx.x & 7) << 7) + tid;    // 0..1023
    size_t base = (size_t)bt * Cc * HW + hw;
    float acc = 0.f;
    #pragma unroll
    for (int c = 0; c < Cc; ++c) acc += wbar[c] * ld1<F32>(x, base + c * HW);

    int b = bt >> 3, t = bt & 7;
    pooled[b * Nn + t * HW + hw] = acc + bbar;
}

__global__ void pool_kernel(const void* __restrict__ x,
                            const void* __restrict__ conv1_w,
                            const void* __restrict__ conv1_b,
                            float* __restrict__ pooled,
                            int* __restrict__ flag) {
    // dtype detect: even uint16 halfwords of a bf16 N(0,1) array have
    // exponent in [0x6F,0x83] ~always; for f32 arrays they are low mantissa
    // bits (~uniform, ~8% pass). 256 samples, threshold 128.
    __shared__ int sflag;
    __shared__ int wcnt[2];
    int tid = threadIdx.x;  // 0..127
    const unsigned short* xs = (const unsigned short*)x;
    unsigned short u0 = xs[4 * tid], u1 = xs[4 * tid + 2];
    int e0 = (u0 >> 7) & 0xFF, e1 = (u1 >> 7) & 0xFF;
    int c = ((e0 >= 0x6F && e0 <= 0x83) ? 1 : 0)
          + ((e1 >= 0x6F && e1 <= 0x83) ? 1 : 0);
    #pragma unroll
    for (int off = 32; off > 0; off >>= 1) c += __shfl_down(c, off);
    if ((tid & 63) == 0) wcnt[tid >> 6] = c;
    __syncthreads();
    if (tid == 0) {
        int f = (wcnt[0] + wcnt[1] < 128) ? 1 : 0;  // 1 => float32 inputs
        sflag = f;
        flag[0] = f;  // all blocks write the same value (benign race)
    }
    __syncthreads();
    if (sflag) pool_body<true>(x, conv1_w, conv1_b, pooled);
    else       pool_body<false>(x, conv1_w, conv1_b, pooled);
}

// ---------------- Kernel 2: v = sigmoid(pooled @ W^T + b) ----------------
// grid = 1024 blocks x 1024 threads; 8 rows per block. Each thread owns a
// fixed 8-wide k-slice: pooled stays in registers across all 8 rows
// (pooled L2 traffic 1 GB -> 128 MB vs the 1-row-per-block version).
template <bool F32>
__device__ __forceinline__ void gemv_body(const void* __restrict__ w,
                                          const void* __restrict__ bias,
                                          const float* __restrict__ pooled,
                                          float* __restrict__ v) {
    int tid = threadIdx.x;          // 0..1023
    int k = tid * 8;                // this thread's k-slice
    int n0 = blockIdx.x * 8;

    float pl[4][8];
    #pragma unroll
    for (int b = 0; b < 4; ++b) {
        float4 p0 = *reinterpret_cast<const float4*>(pooled + b * Nn + k);
        float4 p1 = *reinterpret_cast<const float4*>(pooled + b * Nn + k + 4);
        pl[b][0] = p0.x; pl[b][1] = p0.y; pl[b][2] = p0.z; pl[b][3] = p0.w;
        pl[b][4] = p1.x; pl[b][5] = p1.y; pl[b][6] = p1.z; pl[b][7] = p1.w;
    }

    float acc[8][4];
    #pragma unroll
    for (int r = 0; r < 8; ++r) {
        float wv[8];
        if constexpr (F32) {
            const float* row = (const float*)w + (size_t)(n0 + r) * Nn + k;
            float4 w0 = *reinterpret_cast<const float4*>(row);
            float4 w1 = *reinterpret_cast<const float4*>(row + 4);
            wv[0] = w0.x; wv[1] = w0.y; wv[2] = w0.z; wv[3] = w0.w;
            wv[4] = w1.x; wv[5] = w1.y; wv[6] = w1.z; wv[7] = w1.w;
        } else {
            const bf16* row = (const bf16*)w + (size_t)(n0 + r) * Nn + k;
            uint4 q = *reinterpret_cast<const uint4*>(row);
            wv[0] = __uint_as_float(q.x << 16);
            wv[1] = __uint_as_float(q.x & 0xffff0000u);
            wv[2] = __uint_as_float(q.y << 16);
            wv[3] = __uint_as_float(q.y & 0xffff0000u);
            wv[4] = __uint_as_float(q.z << 16);
            wv[5] = __uint_as_float(q.z & 0xffff0000u);
            wv[6] = __uint_as_float(q.w << 16);
            wv[7] = __uint_as_float(q.w & 0xffff0000u);
        }
        #pragma unroll
        for (int b = 0; b < 4; ++b) {
            float s = 0.f;
            #pragma unroll
            for (int j = 0; j < 8; ++j) s = fmaf(wv[j], pl[b][j], s);
            acc[r][b] = s;
        }
    }

    // batched reduction: 32 (r,b) values per thread -> wave shfl -> LDS -> 32 threads
    #pragma unroll
    for (int r = 0; r < 8; ++r)
        #pragma unroll
        for (int b = 0; b < 4; ++b)
            #pragma unroll
            for (int off = 32; off > 0; off >>= 1)
                acc[r][b] += __shfl_down(acc[r][b], off);

    __shared__ float red[16][32];  // [wave][r*4+b]
    int wave = tid >> 6, lane = tid & 63;
    if (lane == 0) {
        #pragma unroll
        for (int r = 0; r < 8; ++r)
            #pragma unroll
            for (int b = 0; b < 4; ++b)
                red[wave][r * 4 + b] = acc[r][b];
    }
    __syncthreads();
    if (tid < 32) {  // thread tid handles (r=tid>>2, b=tid&3); bank-conflict-free
        int r = tid >> 2, b = tid & 3;
        float s = 0.f;
        #pragma unroll
        for (int wv2 = 0; wv2 < 16; ++wv2) s += red[wv2][tid];
        s += ld1<F32>(bias, n0 + r);
        v[b * Nn + n0 + r] = 1.f / (1.f + __expf(-s));
    }
}

__global__ __launch_bounds__(1024)
void gemv_kernel(const void* __restrict__ w,
                 const void* __restrict__ bias,
                 const float* __restrict__ pooled,
                 float* __restrict__ v,
                 const int* __restrict__ flag) {
    if (flag[0]) gemv_body<true>(w, bias, pooled, v);
    else         gemv_body<false>(w, bias, pooled, v);
}

// ---------------- Kernel 3: out = v * (g3_w . x + g3_b) ----------------
// grid = 256 blocks x 128 threads
template <bool F32>
__device__ __forceinline__ void out_body(const void* __restrict__ x,
                                         const void* __restrict__ g3_w,
                                         const void* __restrict__ g3_b,
                                         const float* __restrict__ v,
                                         void* __restrict__ out) {
    __shared__ float ws[Ff][Cc];  // per-(f,c) reads are wave-uniform: broadcast
    __shared__ float bs[Ff];
    int tid = threadIdx.x;  // 0..127
    for (int i = tid; i < Ff * Cc; i += 128) ws[i >> 6][i & 63] = ld1<F32>(g3_w, i);
    if (tid < Ff) bs[tid] = ld1<F32>(g3_b, tid);
    __syncthreads();

    int bt = blockIdx.x >> 3;
    int hw = ((blockIdx.x & 7) << 7) + tid;
    size_t xbase = (size_t)bt * Cc * HW + hw;

    float xv[Cc];
    #pragma unroll
    for (int c = 0; c < Cc; ++c) xv[c] = ld1<F32>(x, xbase + c * HW);

    int b = bt >> 3, t = bt & 7;
    float vv = v[b * Nn + t * HW + hw];

    size_t obase = (size_t)bt * Ff * HW + hw;
    #pragma unroll
    for (int f = 0; f < Ff; ++f) {
        float acc = bs[f];
        #pragma unroll
        for (int c = 0; c < Cc; ++c) acc = fmaf(ws[f][c], xv[c], acc);
        float r = vv * acc;
        if constexpr (F32) ((float*)out)[obase + f * HW] = r;
        else               ((bf16*)out)[obase + f * HW] = __float2bfloat16(r);
    }
}

__global__ void out_kernel(const void* __restrict__ x,
                           const void* __restrict__ g3_w,
                           const void* __restrict__ g3_b,
                           const float* __restrict__ v,
                           void* __restrict__ out,
                           const int* __restrict__ flag) {
    if (flag[0]) out_body<true>(x, g3_w, g3_b, v, out);
    else         out_body<false>(x, g3_w, g3_b, v, out);
}

extern "C" void kernel_launch(void* const* d_in, const int* in_sizes, int n_in,
                              void* d_out, int out_size, void* d_ws, size_t ws_size,
                              hipStream_t stream) {
    const void* x       = d_in[0];
    // d_in[1] = x1 (unused by the reference forward)
    const void* conv1_w = d_in[2];
    const void* conv1_b = d_in[3];
    const void* g3_w    = d_in[4];
    const void* g3_b    = d_in[5];
    const void* ffnn1_w = d_in[6];
    const void* ffnn1_b = d_in[7];

    int*   flag   = (int*)d_ws;                    // 64 B slot
    float* pooled = (float*)d_ws + 16;             // 4*8192 floats = 128 KB
    float* v      = pooled + 4 * Nn;               // 4*8192 floats = 128 KB

    pool_kernel<<<256, 128, 0, stream>>>(x, conv1_w, conv1_b, pooled, flag);
    gemv_kernel<<<1024, 1024, 0, stream>>>(ffnn1_w, ffnn1_b, pooled, v, flag);
    out_kernel<<<256, 128, 0, stream>>>(x, g3_w, g3_b, v, d_out, flag);
}

// Round 4
// 399.613 us; speedup vs baseline: 1.1301x; 1.0306x over previous
//
#include <hip/hip_runtime.h>
#include <hip/hip_bf16.h>

// Shapes: B=4, T=8, C=64, H=32, W=32, F=16, N=T*H*W=8192, HW=1024.
// pooled[b,n] = sum_c wbar[c]*x[b,t,c,h,w] + bbar   (conv1+avgpool collapsed)
// v[b,n]      = sigmoid(pooled[b,:] . ffnn1_w[n,:] + ffnn1_b[n])
// out[b,t,f,h,w] = v[b,n] * (sum_c g3_w[f,c]*x[b,t,c,h,w] + g3_b[f])
//
// R4: out-stage fused into the gemv kernel. Each gemv block owns 8 rows
// n0..n0+7 = one t, 8 consecutive hw -> it computes v for those rows and
// immediately produces out[b,t,:,hw0..hw0+7] (x slice + g3 staged in LDS).
// v never touches global memory.
//
// DTYPE-ROBUST: inputs may be bf16 or float32. pool_kernel detects the dtype
// from x's bit patterns per-block (all blocks agree; benign same-value race on
// the global flag); gemv reads the flag (stream-ordered).

#define HW 1024
#define Cc 64
#define Ff 16
#define Nn 8192

typedef __hip_bfloat16 bf16;

__device__ __forceinline__ float bf2f(bf16 h) { return __bfloat162float(h); }

template <bool F32>
__device__ __forceinline__ float ld1(const void* p, int i) {
    if constexpr (F32) return ((const float*)p)[i];
    else               return bf2f(((const bf16*)p)[i]);
}

// load 8 consecutive elements as floats (16B-aligned source)
template <bool F32>
__device__ __forceinline__ void ld8(const void* p, size_t i, float* dst) {
    if constexpr (F32) {
        const float* q = (const float*)p + i;
        float4 a = *reinterpret_cast<const float4*>(q);
        float4 b = *reinterpret_cast<const float4*>(q + 4);
        dst[0] = a.x; dst[1] = a.y; dst[2] = a.z; dst[3] = a.w;
        dst[4] = b.x; dst[5] = b.y; dst[6] = b.z; dst[7] = b.w;
    } else {
        const bf16* q = (const bf16*)p + i;
        uint4 u = *reinterpret_cast<const uint4*>(q);
        dst[0] = __uint_as_float(u.x << 16);
        dst[1] = __uint_as_float(u.x & 0xffff0000u);
        dst[2] = __uint_as_float(u.y << 16);
        dst[3] = __uint_as_float(u.y & 0xffff0000u);
        dst[4] = __uint_as_float(u.z << 16);
        dst[5] = __uint_as_float(u.z & 0xffff0000u);
        dst[6] = __uint_as_float(u.w << 16);
        dst[7] = __uint_as_float(u.w & 0xffff0000u);
    }
}

// ---------------- Kernel 1: pooled (+ inline dtype detect) ----------------
// grid = 256 blocks x 128 threads. Each thread owns one (bt, hw) pair.
template <bool F32>
__device__ __forceinline__ void pool_body(const void* __restrict__ x,
                                          const void* __restrict__ conv1_w,
                                          const void* __restrict__ conv1_b,
                                          float* __restrict__ pooled) {
    __shared__ float wbar[Cc];
    __shared__ float bbar;
    int tid = threadIdx.x;  // 0..127
    if (tid < Cc) {
        float s = 0.f;
        #pragma unroll
        for (int f = 0; f < Ff; ++f) s += ld1<F32>(conv1_w, f * Cc + tid);
        wbar[tid] = s * (1.f / 16.f);
    }
    if (tid == 64) {
        float s = 0.f;
        #pragma unroll
        for (int f = 0; f < Ff; ++f) s += ld1<F32>(conv1_b, f);
        bbar = s * (1.f / 16.f);
    }
    __syncthreads();

    int bt = blockIdx.x >> 3;                  // 0..31 (b*8+t)
    int hw = ((blockIdx.x & 7) << 7) + tid;    // 0..1023
    size_t base = (size_t)bt * Cc * HW + hw;
    float acc = 0.f;
    #pragma unroll
    for (int c = 0; c < Cc; ++c) acc += wbar[c] * ld1<F32>(x, base + c * HW);

    int b = bt >> 3, t = bt & 7;
    pooled[b * Nn + t * HW + hw] = acc + bbar;
}

__global__ void pool_kernel(const void* __restrict__ x,
                            const void* __restrict__ conv1_w,
                            const void* __restrict__ conv1_b,
                            float* __restrict__ pooled,
                            int* __restrict__ flag) {
    // dtype detect: even uint16 halfwords of a bf16 N(0,1) array have
    // exponent in [0x6F,0x83] ~always; for f32 arrays they are low mantissa
    // bits (~uniform, ~8% pass). 256 samples, threshold 128.
    __shared__ int sflag;
    __shared__ int wcnt[2];
    int tid = threadIdx.x;  // 0..127
    const unsigned short* xs = (const unsigned short*)x;
    unsigned short u0 = xs[4 * tid], u1 = xs[4 * tid + 2];
    int e0 = (u0 >> 7) & 0xFF, e1 = (u1 >> 7) & 0xFF;
    int c = ((e0 >= 0x6F && e0 <= 0x83) ? 1 : 0)
          + ((e1 >= 0x6F && e1 <= 0x83) ? 1 : 0);
    #pragma unroll
    for (int off = 32; off > 0; off >>= 1) c += __shfl_down(c, off);
    if ((tid & 63) == 0) wcnt[tid >> 6] = c;
    __syncthreads();
    if (tid == 0) {
        int f = (wcnt[0] + wcnt[1] < 128) ? 1 : 0;  // 1 => float32 inputs
        sflag = f;
        flag[0] = f;  // all blocks write the same value (benign race)
    }
    __syncthreads();
    if (sflag) pool_body<true>(x, conv1_w, conv1_b, pooled);
    else       pool_body<false>(x, conv1_w, conv1_b, pooled);
}

// ---------------- Kernel 2 (fused): v = sigmoid(pooled@W^T+b); out ----------
// grid = 1024 blocks x 1024 threads; 8 rows per block (one t, 8 consecutive
// hw). Phase A: gemv+sigmoid into LDS vsh. Phase B: stage x slice + g3 into
// LDS. Phase C: 512 threads emit the 512 outputs of this block.
template <bool F32>
__device__ __forceinline__ void gemv_out_body(const void* __restrict__ w,
                                              const void* __restrict__ bias,
                                              const float* __restrict__ pooled,
                                              const void* __restrict__ x,
                                              const void* __restrict__ g3_w,
                                              const void* __restrict__ g3_b,
                                              void* __restrict__ out) {
    int tid = threadIdx.x;          // 0..1023
    int k = tid * 8;                // this thread's k-slice
    int n0 = blockIdx.x * 8;
    int t   = blockIdx.x >> 7;       // n0 / 1024
    int hw0 = (blockIdx.x & 127) * 8;

    // ---- Phase A: 8-row x 4-batch gemv ----
    float pl[4][8];
    #pragma unroll
    for (int b = 0; b < 4; ++b) {
        float4 p0 = *reinterpret_cast<const float4*>(pooled + b * Nn + k);
        float4 p1 = *reinterpret_cast<const float4*>(pooled + b * Nn + k + 4);
        pl[b][0] = p0.x; pl[b][1] = p0.y; pl[b][2] = p0.z; pl[b][3] = p0.w;
        pl[b][4] = p1.x; pl[b][5] = p1.y; pl[b][6] = p1.z; pl[b][7] = p1.w;
    }

    float acc[8][4];
    #pragma unroll
    for (int r = 0; r < 8; ++r) {
        float wv[8];
        ld8<F32>(w, (size_t)(n0 + r) * Nn + k, wv);
        #pragma unroll
        for (int b = 0; b < 4; ++b) {
            float s = 0.f;
            #pragma unroll
            for (int j = 0; j < 8; ++j) s = fmaf(wv[j], pl[b][j], s);
            acc[r][b] = s;
        }
    }

    #pragma unroll
    for (int r = 0; r < 8; ++r)
        #pragma unroll
        for (int b = 0; b < 4; ++b)
            #pragma unroll
            for (int off = 32; off > 0; off >>= 1)
                acc[r][b] += __shfl_down(acc[r][b], off);

    __shared__ float red[16][32];   // [wave][r*4+b]
    __shared__ float vsh[4][8];     // v[b][i]
    __shared__ float xsh[4][Cc][8]; // x[b][c][i] slice (8 KB)
    __shared__ float ws[Ff][Cc + 1];// +1 pad: banks (f+c)%32, conflict-free
    __shared__ float bs[Ff];

    int wave = tid >> 6, lane = tid & 63;
    if (lane == 0) {
        #pragma unroll
        for (int r = 0; r < 8; ++r)
            #pragma unroll
            for (int b = 0; b < 4; ++b)
                red[wave][r * 4 + b] = acc[r][b];
    }
    __syncthreads();

    // ---- Phase B: finish v; stage x slice + g3 ----
    if (tid < 32) {  // (r=tid>>2, b=tid&3); red reads conflict-free
        int r = tid >> 2, b = tid & 3;
        float s = 0.f;
        #pragma unroll
        for (int wv2 = 0; wv2 < 16; ++wv2) s += red[wv2][tid];
        s += ld1<F32>(bias, n0 + r);
        vsh[b][r] = 1.f / (1.f + __expf(-s));
    }
    if (tid < 256) {  // (b=tid>>6, c=tid&63): one 16B (bf16) / 32B (f32) load
        int b = tid >> 6, c = tid & 63;
        float tmp[8];
        ld8<F32>(x, ((size_t)(b * 8 + t) * Cc + c) * HW + hw0, tmp);
        #pragma unroll
        for (int i = 0; i < 8; ++i) xsh[b][c][i] = tmp[i];
    }
    {   // g3_w: 1024 elems, one per thread
        int f = tid >> 6, c = tid & 63;
        ws[f][c] = ld1<F32>(g3_w, tid);
    }
    if (tid < Ff) bs[tid] = ld1<F32>(g3_b, tid);
    __syncthreads();

    // ---- Phase C: 512 outputs (b,f,i) ----
    if (tid < 512) {
        int b = tid >> 7, f = (tid >> 3) & 15, i = tid & 7;
        float a2 = bs[f];
        #pragma unroll
        for (int c = 0; c < Cc; ++c) a2 = fmaf(ws[f][c], xsh[b][c][i], a2);
        float r = vsh[b][i] * a2;
        size_t oi = ((size_t)(b * 8 + t) * Ff + f) * HW + hw0 + i;
        if constexpr (F32) ((float*)out)[oi] = r;
        else               ((bf16*)out)[oi] = __float2bfloat16(r);
    }
}

__global__ __launch_bounds__(1024)
void gemv_out_kernel(const void* __restrict__ w,
                     const void* __restrict__ bias,
                     const float* __restrict__ pooled,
                     const void* __restrict__ x,
                     const void* __restrict__ g3_w,
                     const void* __restrict__ g3_b,
                     void* __restrict__ out,
                     const int* __restrict__ flag) {
    if (flag[0]) gemv_out_body<true>(w, bias, pooled, x, g3_w, g3_b, out);
    else         gemv_out_body<false>(w, bias, pooled, x, g3_w, g3_b, out);
}

extern "C" void kernel_launch(void* const* d_in, const int* in_sizes, int n_in,
                              void* d_out, int out_size, void* d_ws, size_t ws_size,
                              hipStream_t stream) {
    const void* x       = d_in[0];
    // d_in[1] = x1 (unused by the reference forward)
    const void* conv1_w = d_in[2];
    const void* conv1_b = d_in[3];
    const void* g3_w    = d_in[4];
    const void* g3_b    = d_in[5];
    const void* ffnn1_w = d_in[6];
    const void* ffnn1_b = d_in[7];

    int*   flag   = (int*)d_ws;                    // 64 B slot
    float* pooled = (float*)d_ws + 16;             // 4*8192 floats = 128 KB

    pool_kernel<<<256, 128, 0, stream>>>(x, conv1_w, conv1_b, pooled, flag);
    gemv_out_kernel<<<1024, 1024, 0, stream>>>(ffnn1_w, ffnn1_b, pooled,
                                               x, g3_w, g3_b, d_out, flag);
}